// Round 5
// baseline (4614.428 us; speedup 1.0000x reference)
//
#include <hip/hip_runtime.h>
#include <hip/hip_bf16.h>
#include <hip/hip_cooperative_groups.h>
#include <math.h>

namespace cg = cooperative_groups;

#define H 450
#define HP 464            // padded A row stride (bf16 elems; 16B-aligned rows)
#define KP 480            // padded K extent: 15 MFMA chunks of 32
#define LAT 56
#define V 780
#define LW 24
#define NE 46
#define NF 23
#define SLOT (1024*HP)    // hs slot stride (elems)
#define SROWS 2048
#define QROWS (24*1024)
#define PROWS (47*1024)
#define PTGT  (23*1024)
#define QBLK 6144         // q_reduce blocks (4 rows each)

typedef __hip_bfloat16 bf16;
typedef __attribute__((ext_vector_type(8))) short short8;
typedef __attribute__((ext_vector_type(4))) float f32x4;

#define MFMA16(a,b,c) __builtin_amdgcn_mfma_f32_16x16x32_bf16(a,b,c,0,0,0)

__device__ __forceinline__ float sigm(float x) { return 1.f / (1.f + expf(-x)); }
__device__ __forceinline__ float toF(bf16 x) { return __bfloat162float(x); }
__device__ __forceinline__ void stV(float* p, float v) { *p = v; }
__device__ __forceinline__ void stV(bf16* p, float v) { *p = __float2bfloat16(v); }
__device__ __forceinline__ short8 ld8(const bf16* p) { return *reinterpret_cast<const short8*>(p); }

// ---------------------------------------------------------------------------
__global__ __launch_bounds__(256)
void make_bt(const float* __restrict__ src, int K, int N, int ld,
             bf16* __restrict__ dst, int npad) {
    int idx = blockIdx.x * 256 + threadIdx.x;
    if (idx >= npad * KP) return;
    int n = idx / KP, k = idx - n * KP;
    float v = (n < N && k < K) ? src[(size_t)k * ld + n] : 0.f;
    dst[idx] = __float2bfloat16(v);
}

__global__ __launch_bounds__(256)
void zero_init(float* __restrict__ out, float* __restrict__ Sb, int n) {
    int i = blockIdx.x * 256 + threadIdx.x;
    if (i < 4) out[i] = 0.f;
    if (i < n) Sb[i] = 0.f;
}

// x_all[t*1024+n][h] = emb[wid[n][t]][h]  (bf16, stride HP)
__global__ __launch_bounds__(256)
void gather_x(const float* __restrict__ emb, const int* __restrict__ wid,
              bf16* __restrict__ x_all) {
    int e = blockIdx.x * 256 + threadIdx.x;
    if (e >= 24 * 1024 * 225) return;
    int row = e / 225, h2 = e - row * 225;
    int t = row >> 10, n = row & 1023;
    int v = wid[n * LW + t];
    float2 x = ((const float2*)(emb + (size_t)v * H))[h2];
    bf16* dst = x_all + (size_t)row * HP + 2 * h2;
    dst[0] = __float2bfloat16(x.x);
    dst[1] = __float2bfloat16(x.y);
}

// ---------------------------------------------------------------------------
// Generic MFMA GEMM: C = act(A @ B + bias + addrow[(r&1023)*addld+c])
// ---------------------------------------------------------------------------
template<typename TC>
__global__ __launch_bounds__(256)
void gemm_mfma(const bf16* __restrict__ A, int lda,
               const bf16* __restrict__ Bt, int N,
               TC* __restrict__ C, int ldc,
               const float* __restrict__ bias,
               const float* __restrict__ addrow, int addld, int relu) {
    int tid = threadIdx.x;
    int lane = tid & 63, wave = tid >> 6;
    int wx = wave & 1, wy = wave >> 1;
    int lrow = lane & 15, quad = lane >> 4;
    int row0 = blockIdx.y * 64, col0 = blockIdx.x * 64;
    const bf16* a0 = A + (size_t)(row0 + wy * 32 + lrow) * lda + quad * 8;
    const bf16* a1 = a0 + (size_t)16 * lda;
    const bf16* b0 = Bt + (size_t)(col0 + wx * 32 + lrow) * KP + quad * 8;
    const bf16* b1 = b0 + 16 * KP;
    f32x4 acc[2][2] = {};
    for (int k = 0; k < 15; k++) {
        short8 af0 = ld8(a0 + k * 32);
        short8 af1 = ld8(a1 + k * 32);
        short8 bf0 = ld8(b0 + k * 32);
        short8 bf1 = ld8(b1 + k * 32);
        acc[0][0] = MFMA16(af0, bf0, acc[0][0]);
        acc[0][1] = MFMA16(af0, bf1, acc[0][1]);
        acc[1][0] = MFMA16(af1, bf0, acc[1][0]);
        acc[1][1] = MFMA16(af1, bf1, acc[1][1]);
    }
#pragma unroll
    for (int i = 0; i < 2; i++)
#pragma unroll
        for (int e = 0; e < 4; e++) {
            int r = row0 + wy * 32 + i * 16 + quad * 4 + e;
#pragma unroll
            for (int j = 0; j < 2; j++) {
                int c = col0 + wx * 32 + j * 16 + lrow;
                if (c >= N) continue;
                float v = acc[i][j][e];
                if (bias) v += bias[c];
                if (addrow) v += addrow[(size_t)(r & 1023) * addld + c];
                if (relu) v = fmaxf(v, 0.f);
                stV(&C[(size_t)r * ldc + c], v);
            }
        }
}

// Qtv/Ptv: out[n][c] = tv[n](56) @ Wlat(56x450) + bias[c]   grid(2,1024)
__global__ __launch_bounds__(256)
void tv_gemm(const float* __restrict__ tv, const float* __restrict__ Wlat,
             const float* __restrict__ bias, float* __restrict__ out) {
    int n = blockIdx.y;
    int c = blockIdx.x * 256 + threadIdx.x;
    __shared__ float tvs[LAT];
    if (threadIdx.x < LAT) tvs[threadIdx.x] = tv[n * LAT + threadIdx.x];
    __syncthreads();
    if (c < H) {
        float a = bias[c];
#pragma unroll 8
        for (int k = 0; k < LAT; k++) a += tvs[k] * Wlat[(size_t)k * H + c];
        out[(size_t)n * H + c] = a;
    }
}

// ---------------------------------------------------------------------------
// Cooperative persistent scan: 23 steps x (phase1: z/h GEMM+state update,
// phase2: r GEMM+RM), grid.sync between phases; hv fixup tail.
// grid = 256 blocks x 256 threads (1 block/CU).
// ---------------------------------------------------------------------------
__global__ __launch_bounds__(256, 1)
void scan_all(bf16* hs, bf16* RMb,
              const bf16* __restrict__ WzbT, const bf16* __restrict__ WhbT,
              const bf16* __restrict__ UrT,
              const bf16* __restrict__ Xz, const bf16* __restrict__ Xh,
              const bf16* __restrict__ Xr, float* Sb) {
    cg::grid_group grid = cg::this_grid();
    int tid = threadIdx.x;
    int lane = tid & 63, wave = tid >> 6;
    int wx = wave & 1, wy = wave >> 1;
    int lrow = lane & 15, quad = lane >> 4;
    int bid = blockIdx.x;                     // 0..255
    int cx = bid & 7, ry = bid >> 3;
    int row0 = ry * 64, col0 = cx * 64;
    bool fwd = row0 < 1024;
    int rb = row0 & 1023;

    for (int u = 0; u < 23; u++) {
        // ---- phase 1: z_pre = S@Wzb, h_pre = RM@Whb; m_new update ----
        {
            f32x4 az[2][2] = {}, ah[2][2] = {};
            if (u > 0) {
                const bf16* As = hs + (size_t)(fwd ? (u - 1) : (22 + u)) * SLOT
                                 + (size_t)(rb + wy * 32 + lrow) * HP + quad * 8;
                const bf16* Ar = RMb + (size_t)(row0 + wy * 32 + lrow) * HP + quad * 8;
                const bf16* bz0 = WzbT + (size_t)(col0 + wx * 32 + lrow) * KP + quad * 8;
                const bf16* bh0 = WhbT + (size_t)(col0 + wx * 32 + lrow) * KP + quad * 8;
                for (int k = 0; k < 15; k++) {
                    short8 s0 = ld8(As + k * 32);
                    short8 s1 = ld8(As + (size_t)16 * HP + k * 32);
                    short8 r0 = ld8(Ar + k * 32);
                    short8 r1 = ld8(Ar + (size_t)16 * HP + k * 32);
                    short8 z0 = ld8(bz0 + k * 32);
                    short8 z1 = ld8(bz0 + 16 * KP + k * 32);
                    short8 h0 = ld8(bh0 + k * 32);
                    short8 h1 = ld8(bh0 + 16 * KP + k * 32);
                    az[0][0] = MFMA16(s0, z0, az[0][0]);
                    az[0][1] = MFMA16(s0, z1, az[0][1]);
                    az[1][0] = MFMA16(s1, z0, az[1][0]);
                    az[1][1] = MFMA16(s1, z1, az[1][1]);
                    ah[0][0] = MFMA16(r0, h0, ah[0][0]);
                    ah[0][1] = MFMA16(r0, h1, ah[0][1]);
                    ah[1][0] = MFMA16(r1, h0, ah[1][0]);
                    ah[1][1] = MFMA16(r1, h1, ah[1][1]);
                }
            }
            int src = fwd ? u : 23 - u;
            bf16* hso = hs + (size_t)(fwd ? u : 23 + u) * SLOT;
#pragma unroll
            for (int i = 0; i < 2; i++)
#pragma unroll
                for (int e = 0; e < 4; e++) {
                    int r = row0 + wy * 32 + i * 16 + quad * 4 + e;
                    int n = r & 1023;
#pragma unroll
                    for (int j = 0; j < 2; j++) {
                        int c = col0 + wx * 32 + j * 16 + lrow;
                        if (c >= H) continue;
                        float zp = az[i][j][e] + toF(Xz[((size_t)src * 1024 + n) * H + c]);
                        float hp = ah[i][j][e] + toF(Xh[((size_t)src * 1024 + n) * H + c]);
                        float s  = Sb[(size_t)r * H + c];
                        float z  = sigm(zp);
                        float mt = tanhf(hp);
                        float mn = (1.f - z) * s + z * mt;
                        Sb[(size_t)r * H + c] = mn;
                        hso[(size_t)n * HP + c] = __float2bfloat16(mn);
                    }
                }
        }
        __threadfence();
        grid.sync();
        __threadfence();

        // ---- phase 2: r_pre = Mnew@Ur + Xr[dst]; RM (skip last step) ----
        if (u < 22) {
            const bf16* Am = hs + (size_t)(fwd ? u : 23 + u) * SLOT
                             + (size_t)(rb + wy * 32 + lrow) * HP + quad * 8;
            const bf16* b0 = UrT + (size_t)(col0 + wx * 32 + lrow) * KP + quad * 8;
            f32x4 acc[2][2] = {};
            for (int k = 0; k < 15; k++) {
                short8 a0 = ld8(Am + k * 32);
                short8 a1 = ld8(Am + (size_t)16 * HP + k * 32);
                short8 w0 = ld8(b0 + k * 32);
                short8 w1 = ld8(b0 + 16 * KP + k * 32);
                acc[0][0] = MFMA16(a0, w0, acc[0][0]);
                acc[0][1] = MFMA16(a0, w1, acc[0][1]);
                acc[1][0] = MFMA16(a1, w0, acc[1][0]);
                acc[1][1] = MFMA16(a1, w1, acc[1][1]);
            }
            int dst = fwd ? (u + 1) : (22 - u);
#pragma unroll
            for (int i = 0; i < 2; i++)
#pragma unroll
                for (int e = 0; e < 4; e++) {
                    int r = row0 + wy * 32 + i * 16 + quad * 4 + e;
                    int n = r & 1023;
#pragma unroll
                    for (int j = 0; j < 2; j++) {
                        int c = col0 + wx * 32 + j * 16 + lrow;
                        if (c >= H) continue;
                        float rp = acc[i][j][e] + toF(Xr[((size_t)dst * 1024 + n) * H + c]);
                        float rr = sigm(rp);
                        RMb[(size_t)r * HP + c] = __float2bfloat16(rr * Sb[(size_t)r * H + c]);
                    }
                }
            __threadfence();
            grid.sync();
            __threadfence();
        }
    }

    // ---- hv fixup tail: hs[23+tl] += hs[21-tl], tl in [0,22) ----
    int total = 22 * SLOT;
    for (int idx = blockIdx.x * 256 + tid; idx < total; idx += 256 * 256) {
        int tl = idx / SLOT, rem = idx - tl * SLOT;
        size_t a = (size_t)(23 + tl) * SLOT + rem;
        size_t b = (size_t)(21 - tl) * SLOT + rem;
        hs[a] = __float2bfloat16(toF(hs[a]) + toF(hs[b]));
    }
}

// q_hidden root rows: relu(Qtv) -> qh rows 0..1023 (stride HP)
__global__ __launch_bounds__(256)
void q_root(const float* __restrict__ Qtv, bf16* __restrict__ qh) {
    int idx = blockIdx.x * 256 + threadIdx.x;
    if (idx >= 1024 * H) return;
    int n = idx / H, c = idx - n * H;
    qh[(size_t)n * HP + c] = __float2bfloat16(fmaxf(Qtv[idx], 0.f));
}

// ---------------------------------------------------------------------------
// q_reduce: wave-per-row online softmax + argmax; per-block partials -> qred
// grid = 6144 blocks x 256 threads (4 rows/block)
// ---------------------------------------------------------------------------
__global__ __launch_bounds__(256)
void q_reduce(const float* __restrict__ ql, const int* __restrict__ wid,
              float* __restrict__ qred) {
    int wave = threadIdx.x >> 6, lane = threadIdx.x & 63;
    int r = blockIdx.x * 4 + wave;                 // 0..24575
    int t = r >> 10, n = r & 1023;
    int tgt = wid[n * LW + t];
    const float4* row4 = (const float4*)(ql + (size_t)r * V);   // 195 float4
    float m = -3.4e38f, s = 0.f; int mi = 0x7fffffff;
#pragma unroll
    for (int k = 0; k < 4; k++) {
        int c4 = lane + 64 * k;
        if (c4 < 195) {
            float4 v4 = row4[c4];
            float vv[4] = {v4.x, v4.y, v4.z, v4.w};
#pragma unroll
            for (int e = 0; e < 4; e++) {
                float v = vv[e];
                if (v > m) { s = s * __expf(m - v) + 1.f; m = v; mi = c4 * 4 + e; }
                else s += __expf(v - m);
            }
        }
    }
#pragma unroll
    for (int off = 1; off < 64; off <<= 1) {
        float m2 = __shfl_xor(m, off);
        float s2 = __shfl_xor(s, off);
        int   i2 = __shfl_xor(mi, off);
        if (m2 > m || (m2 == m && i2 < mi)) {
            s = s2 + s * __expf(m - m2);
            m = m2; mi = i2;
        } else {
            s = s + s2 * __expf(m2 - m);
        }
    }
    __shared__ float lred[4][2];
    if (lane == 0) {
        float lse = m + logf(s);
        lred[wave][0] = lse - ql[(size_t)r * V + tgt];
        lred[wave][1] = (mi == tgt) ? 1.f : 0.f;
    }
    __syncthreads();
    if (threadIdx.x == 0) {
        qred[blockIdx.x * 2]     = lred[0][0] + lred[1][0] + lred[2][0] + lred[3][0];
        qred[blockIdx.x * 2 + 1] = lred[0][1] + lred[1][1] + lred[2][1] + lred[3][1];
    }
}

// final q reduction: one block
__global__ __launch_bounds__(256)
void q_final(const float* __restrict__ qred, float* __restrict__ out) {
    int tid = threadIdx.x;
    float L = 0.f, A = 0.f;
    for (int i = tid; i < QBLK; i += 256) { L += qred[2 * i]; A += qred[2 * i + 1]; }
    __shared__ float s1[256], s2[256];
    s1[tid] = L; s2[tid] = A;
    __syncthreads();
    for (int k = 128; k > 0; k >>= 1) {
        if (tid < k) { s1[tid] += s1[tid + k]; s2[tid] += s2[tid + k]; }
        __syncthreads();
    }
    if (tid == 0) {
        out[0] = s1[0] * (1.f / 1024.f);
        out[2] = s2[0] * (1.f / 24576.f);
    }
}

__global__ __launch_bounds__(256)
void p_init(float* __restrict__ pl, const float* __restrict__ Us_b) {
    int idx = blockIdx.x * 256 + threadIdx.x;
    if (idx < PROWS) pl[idx] = Us_b[0];
}

__global__ __launch_bounds__(256)
void p_root(const bf16* __restrict__ XUa, const float* __restrict__ Ptv,
            const float* __restrict__ Us, float* __restrict__ pl) {
    int n = blockIdx.x;
    int tid = threadIdx.x;
    const bf16* xa = XUa + (size_t)n * H;
    const float* pt = Ptv + (size_t)n * H;
    float s = 0.f;
    for (int c = tid; c < H; c += 256)
        s += fmaxf(toF(xa[c]) + pt[c], 0.f) * Us[c];
    __shared__ float red[256];
    red[tid] = s;
    __syncthreads();
    for (int k = 128; k > 0; k >>= 1) {
        if (tid < k) red[tid] += red[tid + k];
        __syncthreads();
    }
    if (tid == 0) atomicAdd(&pl[n], red[0]);
}

// p scan rows (MFMA): hs @ Ub; epilogue relu(+XUa[dst]+Ptv) dot Us -> pl
__global__ __launch_bounds__(256)
void p_gemm(const bf16* __restrict__ hs, const bf16* __restrict__ UbT,
            const bf16* __restrict__ XUa, const float* __restrict__ Ptv,
            const float* __restrict__ Us, float* __restrict__ pl) {
    int tid = threadIdx.x;
    int lane = tid & 63, wave = tid >> 6;
    int wx = wave & 1, wy = wave >> 1;
    int lrow = lane & 15, quad = lane >> 4;
    int row0 = blockIdx.y * 64, col0 = blockIdx.x * 64;
    const bf16* a0 = hs + (size_t)(row0 + wy * 32 + lrow) * HP + quad * 8;
    const bf16* b0 = UbT + (size_t)(col0 + wx * 32 + lrow) * KP + quad * 8;
    f32x4 acc[2][2] = {};
    for (int k = 0; k < 15; k++) {
        short8 af0 = ld8(a0 + k * 32);
        short8 af1 = ld8(a0 + (size_t)16 * HP + k * 32);
        short8 bf0 = ld8(b0 + k * 32);
        short8 bf1 = ld8(b0 + 16 * KP + k * 32);
        acc[0][0] = MFMA16(af0, bf0, acc[0][0]);
        acc[0][1] = MFMA16(af0, bf1, acc[0][1]);
        acc[1][0] = MFMA16(af1, bf0, acc[1][0]);
        acc[1][1] = MFMA16(af1, bf1, acc[1][1]);
    }
    __shared__ float red[64][32];
#pragma unroll
    for (int i = 0; i < 2; i++)
#pragma unroll
        for (int e = 0; e < 4; e++) {
            int rl = wy * 32 + i * 16 + quad * 4 + e;
            int r = row0 + rl;
            int t = r >> 10, n = r & 1023;
            int dst = (t < 23) ? (t + 1) : (45 - t);
            float partial = 0.f;
#pragma unroll
            for (int j = 0; j < 2; j++) {
                int c = col0 + wx * 32 + j * 16 + lrow;
                if (c < H) {
                    float h = fmaxf(acc[i][j][e] + toF(XUa[((size_t)dst * 1024 + n) * H + c])
                                    + Ptv[(size_t)n * H + c], 0.f);
                    partial += h * Us[c];
                }
            }
            red[rl][wx * 16 + lrow] = partial;
        }
    __syncthreads();
    if (tid < 64) {
        float s = 0.f;
#pragma unroll
        for (int k = 0; k < 32; k++) s += red[tid][k];
        atomicAdd(&pl[1024 + row0 + tid], s);
    }
}

// BCE loss + accuracy over 48128 rows; target = (r < 23552)
__global__ __launch_bounds__(256)
void p_final(const float* __restrict__ pl, float* __restrict__ out) {
    int r = blockIdx.x * 256 + threadIdx.x;
    int tid = threadIdx.x;
    float loss = 0.f, acc = 0.f;
    if (r < PROWS) {
        float l = pl[r];
        int tgt = (r < PTGT) ? 1 : 0;
        float x = tgt ? -l : l;
        loss = fmaxf(x, 0.f) + log1pf(expf(-fabsf(x)));
        int pred = (l > 0.f) ? 1 : 0;
        acc = (pred == tgt) ? 1.f : 0.f;
    }
    __shared__ float s1[256], s2[256];
    s1[tid] = loss; s2[tid] = acc;
    __syncthreads();
    for (int k = 128; k > 0; k >>= 1) {
        if (tid < k) { s1[tid] += s1[tid + k]; s2[tid] += s2[tid + k]; }
        __syncthreads();
    }
    if (tid == 0) {
        atomicAdd(&out[1], s1[0] * (1.f / 1024.f));
        atomicAdd(&out[3], s2[0] * (1.f / 48128.f));
    }
}

// ---------------------------------------------------------------------------
extern "C" void kernel_launch(void* const* d_in, const int* in_sizes, int n_in,
                              void* d_out, int out_size, void* d_ws, size_t ws_size,
                              hipStream_t stream) {
    const int*   wid  = (const int*)  d_in[0];
    const float* tv   = (const float*)d_in[1];
    const float* emb  = (const float*)d_in[2];
    const float* W_w  = (const float*)d_in[3];
    const float* W_b  = (const float*)d_in[4];
    const float* U_w  = (const float*)d_in[5];
    const float* U_b  = (const float*)d_in[6];
    const float* Wo_w = (const float*)d_in[7];
    const float* Wo_b = (const float*)d_in[8];
    const float* Us_w = (const float*)d_in[9];
    const float* Us_b = (const float*)d_in[10];
    const float* Wz_w = (const float*)d_in[11];
    const float* Wz_b = (const float*)d_in[12];
    const float* Wr_w = (const float*)d_in[13];
    const float* Ur_w = (const float*)d_in[14];
    const float* Ur_b = (const float*)d_in[15];
    const float* Wh_w = (const float*)d_in[16];
    const float* Wh_b = (const float*)d_in[17];
    float* out = (float*)d_out;

    // ---- workspace layout (bytes), total ~147 MiB ----
    char* base = (char*)d_ws;
    const size_t XBb = (size_t)QROWS * H * 2;
    bf16*  Xz   = (bf16*)(base);
    bf16*  Xh   = (bf16*)(base + XBb);
    bf16*  Xr   = (bf16*)(base + 2 * XBb);
    bf16*  XUa  = (bf16*)(base + 3 * XBb);
    bf16*  hs   = (bf16*)(base + 4 * XBb);               // 46 slots x 1024 x HP
    bf16*  x_all = hs;                                   // alias (dead before scan)
    char*  p1   = base + 4 * XBb + (size_t)NE * SLOT * 2;
    bf16*  RMb  = (bf16*)p1;                p1 += (size_t)SROWS * HP * 2;
    float* Sb   = (float*)p1;               p1 += (size_t)SROWS * H * 4;
    float* Qtv  = (float*)p1;               p1 += (size_t)1024 * H * 4;
    float* Ptv  = (float*)p1;               p1 += (size_t)1024 * H * 4;
    float* pl   = (float*)p1;               p1 += (size_t)PROWS * 4;
    float* qred = (float*)p1;               p1 += (size_t)QBLK * 2 * 4;
    bf16*  BT   = (bf16*)p1;
    const size_t BTS = (size_t)512 * KP;
    bf16 *WztT = BT,           *WhtT = BT + BTS,     *WrT = BT + 2*BTS,
         *UaT  = BT + 3*BTS,   *WzbT = BT + 4*BTS,   *WhbT = BT + 5*BTS,
         *UrT  = BT + 6*BTS,   *UbT  = BT + 7*BTS,   *WtopT = BT + 8*BTS,
         *WoT  = BT + 9*BTS;                             // 832*KP
    // q-path aliases (used after p path completes):
    bf16*  qh = (bf16*)base;                             // 24576 x HP bf16
    float* ql = (float*)(base + (size_t)QROWS * HP * 2); // 24576 x 780 f32

    // ---- init + weight prep ----
    zero_init<<<(SROWS * H + 255) / 256, 256, 0, stream>>>(out, Sb, SROWS * H);
    int btg = (512 * KP + 255) / 256;
    make_bt<<<btg, 256, 0, stream>>>(Wz_w,            H, H, H, WztT, 512);
    make_bt<<<btg, 256, 0, stream>>>(Wh_w,            H, H, H, WhtT, 512);
    make_bt<<<btg, 256, 0, stream>>>(Wr_w,            H, H, H, WrT,  512);
    make_bt<<<btg, 256, 0, stream>>>(U_w,             H, H, H, UaT,  512);
    make_bt<<<btg, 256, 0, stream>>>(Wz_w + 450*450,  H, H, H, WzbT, 512);
    make_bt<<<btg, 256, 0, stream>>>(Wh_w + 450*450,  H, H, H, WhbT, 512);
    make_bt<<<btg, 256, 0, stream>>>(Ur_w,            H, H, H, UrT,  512);
    make_bt<<<btg, 256, 0, stream>>>(U_w + 450*450,   H, H, H, UbT,  512);
    make_bt<<<btg, 256, 0, stream>>>(W_w,             H, H, H, WtopT, 512);
    make_bt<<<(832 * KP + 255) / 256, 256, 0, stream>>>(Wo_w, H, V, V, WoT, 832);

    // ---- embedding gather + per-node precomputes ----
    gather_x<<<(24 * 1024 * 225 + 255) / 256, 256, 0, stream>>>(emb, wid, x_all);
    dim3 gPre(8, QROWS / 64);
    gemm_mfma<bf16><<<gPre, 256, 0, stream>>>(x_all, HP, WztT, H, Xz,  H, Wz_b, (const float*)nullptr, H, 0);
    gemm_mfma<bf16><<<gPre, 256, 0, stream>>>(x_all, HP, WhtT, H, Xh,  H, Wh_b, (const float*)nullptr, H, 0);
    gemm_mfma<bf16><<<gPre, 256, 0, stream>>>(x_all, HP, WrT,  H, Xr,  H, Ur_b, (const float*)nullptr, H, 0);
    gemm_mfma<bf16><<<gPre, 256, 0, stream>>>(x_all, HP, UaT,  H, XUa, H, (const float*)nullptr, (const float*)nullptr, H, 0);

    tv_gemm<<<dim3(2, 1024), 256, 0, stream>>>(tv, W_w + 450*450, W_b, Qtv);
    tv_gemm<<<dim3(2, 1024), 256, 0, stream>>>(tv, U_w + 900*450, U_b, Ptv);

    // ---- cooperative persistent scan (23 steps, 45 grid syncs, fixup tail) ----
    {
        void* sargs[] = { (void*)&hs, (void*)&RMb, (void*)&WzbT, (void*)&WhbT,
                          (void*)&UrT, (void*)&Xz, (void*)&Xh, (void*)&Xr, (void*)&Sb };
        hipLaunchCooperativeKernel(reinterpret_cast<void*>(scan_all),
                                   dim3(256), dim3(256), sargs, 0, stream);
    }

    // ---- p path (before q aliases X blocks / hs) ----
    p_init<<<(PROWS + 255) / 256, 256, 0, stream>>>(pl, Us_b);
    p_root<<<1024, 256, 0, stream>>>(XUa, Ptv, Us_w, pl);
    dim3 gP(8, (NE * 1024) / 64);
    p_gemm<<<gP, 256, 0, stream>>>(hs, UbT, XUa, Ptv, Us_w, pl);
    p_final<<<PROWS / 256, 256, 0, stream>>>(pl, out);

    // ---- q path (qh over Xz/Xh; ql over Xr/XUa/hs-head) ----
    q_root<<<(1024 * H + 255) / 256, 256, 0, stream>>>(Qtv, qh);
    dim3 gQh(8, (NF * 1024) / 64);
    gemm_mfma<bf16><<<gQh, 256, 0, stream>>>(hs, HP, WtopT, H, qh + (size_t)1024 * HP, HP,
                                             (const float*)nullptr, Qtv, H, 1);
    dim3 gQl(13, QROWS / 64);
    gemm_mfma<float><<<gQl, 256, 0, stream>>>(qh, HP, WoT, V, ql, V, Wo_b, (const float*)nullptr, H, 0);
    q_reduce<<<QBLK, 256, 0, stream>>>(ql, wid, qred);
    q_final<<<1, 256, 0, stream>>>(qred, out);

    (void)in_sizes; (void)n_in; (void)out_size; (void)ws_size;
}

// Round 6
// 1504.560 us; speedup vs baseline: 3.0670x; 3.0670x over previous
//
#include <hip/hip_runtime.h>
#include <hip/hip_bf16.h>
#include <math.h>

#define H 450
#define HP 464            // padded A row stride (bf16 elems; 16B-aligned rows)
#define KP 480            // padded K extent: 15 MFMA chunks of 32
#define LAT 56
#define V 780
#define LW 24
#define NE 46
#define NF 23
#define SLOT (1024*HP)    // hs slot stride (elems)
#define SROWS 2048
#define QROWS (24*1024)
#define PROWS (47*1024)
#define PTGT  (23*1024)
#define QBLK 6144         // q_reduce blocks (4 rows each)

typedef __hip_bfloat16 bf16;
typedef __attribute__((ext_vector_type(8))) short short8;
typedef __attribute__((ext_vector_type(4))) float f32x4;

#define MFMA16(a,b,c) __builtin_amdgcn_mfma_f32_16x16x32_bf16(a,b,c,0,0,0)

__device__ __forceinline__ float sigm(float x) { return 1.f / (1.f + expf(-x)); }
__device__ __forceinline__ float toF(bf16 x) { return __bfloat162float(x); }
__device__ __forceinline__ void stV(float* p, float v) { *p = v; }
__device__ __forceinline__ void stV(bf16* p, float v) { *p = __float2bfloat16(v); }
__device__ __forceinline__ short8 ld8(const bf16* p) { return *reinterpret_cast<const short8*>(p); }

// ---------------------------------------------------------------------------
__global__ __launch_bounds__(256)
void make_bt(const float* __restrict__ src, int K, int N, int ld,
             bf16* __restrict__ dst, int npad) {
    int idx = blockIdx.x * 256 + threadIdx.x;
    if (idx >= npad * KP) return;
    int n = idx / KP, k = idx - n * KP;
    float v = (n < N && k < K) ? src[(size_t)k * ld + n] : 0.f;
    dst[idx] = __float2bfloat16(v);
}

__global__ __launch_bounds__(256)
void zero_init(float* __restrict__ out, float* __restrict__ Sb, int n) {
    int i = blockIdx.x * 256 + threadIdx.x;
    if (i < 4) out[i] = 0.f;
    if (i < n) Sb[i] = 0.f;
}

// x_all[t*1024+n][h] = emb[wid[n][t]][h]  (bf16, stride HP)
__global__ __launch_bounds__(256)
void gather_x(const float* __restrict__ emb, const int* __restrict__ wid,
              bf16* __restrict__ x_all) {
    int e = blockIdx.x * 256 + threadIdx.x;
    if (e >= 24 * 1024 * 225) return;
    int row = e / 225, h2 = e - row * 225;
    int t = row >> 10, n = row & 1023;
    int v = wid[n * LW + t];
    float2 x = ((const float2*)(emb + (size_t)v * H))[h2];
    bf16* dst = x_all + (size_t)row * HP + 2 * h2;
    dst[0] = __float2bfloat16(x.x);
    dst[1] = __float2bfloat16(x.y);
}

// ---------------------------------------------------------------------------
// Generic MFMA GEMM: C = act(A @ B + bias + addrow[(r&1023)*addld+c])
// ---------------------------------------------------------------------------
template<typename TC>
__global__ __launch_bounds__(256)
void gemm_mfma(const bf16* __restrict__ A, int lda,
               const bf16* __restrict__ Bt, int N,
               TC* __restrict__ C, int ldc,
               const float* __restrict__ bias,
               const float* __restrict__ addrow, int addld, int relu) {
    int tid = threadIdx.x;
    int lane = tid & 63, wave = tid >> 6;
    int wx = wave & 1, wy = wave >> 1;
    int lrow = lane & 15, quad = lane >> 4;
    int row0 = blockIdx.y * 64, col0 = blockIdx.x * 64;
    const bf16* a0 = A + (size_t)(row0 + wy * 32 + lrow) * lda + quad * 8;
    const bf16* a1 = a0 + (size_t)16 * lda;
    const bf16* b0 = Bt + (size_t)(col0 + wx * 32 + lrow) * KP + quad * 8;
    const bf16* b1 = b0 + 16 * KP;
    f32x4 acc[2][2] = {};
    for (int k = 0; k < 15; k++) {
        short8 af0 = ld8(a0 + k * 32);
        short8 af1 = ld8(a1 + k * 32);
        short8 bf0 = ld8(b0 + k * 32);
        short8 bf1 = ld8(b1 + k * 32);
        acc[0][0] = MFMA16(af0, bf0, acc[0][0]);
        acc[0][1] = MFMA16(af0, bf1, acc[0][1]);
        acc[1][0] = MFMA16(af1, bf0, acc[1][0]);
        acc[1][1] = MFMA16(af1, bf1, acc[1][1]);
    }
#pragma unroll
    for (int i = 0; i < 2; i++)
#pragma unroll
        for (int e = 0; e < 4; e++) {
            int r = row0 + wy * 32 + i * 16 + quad * 4 + e;
#pragma unroll
            for (int j = 0; j < 2; j++) {
                int c = col0 + wx * 32 + j * 16 + lrow;
                if (c >= N) continue;
                float v = acc[i][j][e];
                if (bias) v += bias[c];
                if (addrow) v += addrow[(size_t)(r & 1023) * addld + c];
                if (relu) v = fmaxf(v, 0.f);
                stV(&C[(size_t)r * ldc + c], v);
            }
        }
}

// Qtv/Ptv: out[n][c] = tv[n](56) @ Wlat(56x450) + bias[c]   grid(2,1024)
__global__ __launch_bounds__(256)
void tv_gemm(const float* __restrict__ tv, const float* __restrict__ Wlat,
             const float* __restrict__ bias, float* __restrict__ out) {
    int n = blockIdx.y;
    int c = blockIdx.x * 256 + threadIdx.x;
    __shared__ float tvs[LAT];
    if (threadIdx.x < LAT) tvs[threadIdx.x] = tv[n * LAT + threadIdx.x];
    __syncthreads();
    if (c < H) {
        float a = bias[c];
#pragma unroll 8
        for (int k = 0; k < LAT; k++) a += tvs[k] * Wlat[(size_t)k * H + c];
        out[(size_t)n * H + c] = a;
    }
}

// ---------------------------------------------------------------------------
// Scan K1 (MFMA): z_pre = S@Wzb, h_pre = RM@Whb  (M=2048,N=450,K=450)
// ---------------------------------------------------------------------------
__global__ __launch_bounds__(256)
void scan_k1(const bf16* __restrict__ AsF, const bf16* __restrict__ AsB,
             const bf16* __restrict__ Arm,
             const bf16* __restrict__ BzT, const bf16* __restrict__ BhT,
             const bf16* __restrict__ Xz, const bf16* __restrict__ Xh,
             float* __restrict__ Sb, bf16* __restrict__ hsF, bf16* __restrict__ hsB,
             int u, int skip) {
    int tid = threadIdx.x;
    int lane = tid & 63, wave = tid >> 6;
    int wx = wave & 1, wy = wave >> 1;
    int lrow = lane & 15, quad = lane >> 4;
    int row0 = blockIdx.y * 64, col0 = blockIdx.x * 64;
    bool fwd = row0 < 1024;
    int rb = row0 & 1023;
    f32x4 az[2][2] = {}, ah[2][2] = {};
    if (!skip) {
        const bf16* As = (fwd ? AsF : AsB) + (size_t)(rb + wy * 32 + lrow) * HP + quad * 8;
        const bf16* Ar = Arm + (size_t)(row0 + wy * 32 + lrow) * HP + quad * 8;
        const bf16* bz0 = BzT + (size_t)(col0 + wx * 32 + lrow) * KP + quad * 8;
        const bf16* bh0 = BhT + (size_t)(col0 + wx * 32 + lrow) * KP + quad * 8;
        for (int k = 0; k < 15; k++) {
            short8 s0 = ld8(As + k * 32);
            short8 s1 = ld8(As + (size_t)16 * HP + k * 32);
            short8 r0 = ld8(Ar + k * 32);
            short8 r1 = ld8(Ar + (size_t)16 * HP + k * 32);
            short8 z0 = ld8(bz0 + k * 32);
            short8 z1 = ld8(bz0 + 16 * KP + k * 32);
            short8 h0 = ld8(bh0 + k * 32);
            short8 h1 = ld8(bh0 + 16 * KP + k * 32);
            az[0][0] = MFMA16(s0, z0, az[0][0]);
            az[0][1] = MFMA16(s0, z1, az[0][1]);
            az[1][0] = MFMA16(s1, z0, az[1][0]);
            az[1][1] = MFMA16(s1, z1, az[1][1]);
            ah[0][0] = MFMA16(r0, h0, ah[0][0]);
            ah[0][1] = MFMA16(r0, h1, ah[0][1]);
            ah[1][0] = MFMA16(r1, h0, ah[1][0]);
            ah[1][1] = MFMA16(r1, h1, ah[1][1]);
        }
    }
    int src = fwd ? u : 23 - u;
    bf16* hso = fwd ? hsF : hsB;
#pragma unroll
    for (int i = 0; i < 2; i++)
#pragma unroll
        for (int e = 0; e < 4; e++) {
            int r = row0 + wy * 32 + i * 16 + quad * 4 + e;
            int n = r & 1023;
#pragma unroll
            for (int j = 0; j < 2; j++) {
                int c = col0 + wx * 32 + j * 16 + lrow;
                if (c >= H) continue;
                float zp = az[i][j][e] + toF(Xz[((size_t)src * 1024 + n) * H + c]);
                float hp = ah[i][j][e] + toF(Xh[((size_t)src * 1024 + n) * H + c]);
                float s  = Sb[(size_t)r * H + c];
                float z  = sigm(zp);
                float mt = tanhf(hp);
                float mn = (1.f - z) * s + z * mt;
                Sb[(size_t)r * H + c] = mn;
                hso[(size_t)n * HP + c] = __float2bfloat16(mn);
            }
        }
}

// Scan K2 (MFMA): r_pre = Mnew@Ur + Xr[dst]; RMb = bf16(sig(r_pre)*Mnew)
__global__ __launch_bounds__(256)
void scan_k2(const bf16* __restrict__ AmF, const bf16* __restrict__ AmB,
             const bf16* __restrict__ UrT, const bf16* __restrict__ Xr,
             const float* __restrict__ Sb, bf16* __restrict__ RMb, int u) {
    int tid = threadIdx.x;
    int lane = tid & 63, wave = tid >> 6;
    int wx = wave & 1, wy = wave >> 1;
    int lrow = lane & 15, quad = lane >> 4;
    int row0 = blockIdx.y * 64, col0 = blockIdx.x * 64;
    bool fwd = row0 < 1024;
    int rb = row0 & 1023;
    const bf16* Am = (fwd ? AmF : AmB) + (size_t)(rb + wy * 32 + lrow) * HP + quad * 8;
    const bf16* b0 = UrT + (size_t)(col0 + wx * 32 + lrow) * KP + quad * 8;
    f32x4 acc[2][2] = {};
    for (int k = 0; k < 15; k++) {
        short8 a0 = ld8(Am + k * 32);
        short8 a1 = ld8(Am + (size_t)16 * HP + k * 32);
        short8 w0 = ld8(b0 + k * 32);
        short8 w1 = ld8(b0 + 16 * KP + k * 32);
        acc[0][0] = MFMA16(a0, w0, acc[0][0]);
        acc[0][1] = MFMA16(a0, w1, acc[0][1]);
        acc[1][0] = MFMA16(a1, w0, acc[1][0]);
        acc[1][1] = MFMA16(a1, w1, acc[1][1]);
    }
    int dst = fwd ? (u + 1) : (22 - u);
#pragma unroll
    for (int i = 0; i < 2; i++)
#pragma unroll
        for (int e = 0; e < 4; e++) {
            int r = row0 + wy * 32 + i * 16 + quad * 4 + e;
            int n = r & 1023;
#pragma unroll
            for (int j = 0; j < 2; j++) {
                int c = col0 + wx * 32 + j * 16 + lrow;
                if (c >= H) continue;
                float rp = acc[i][j][e] + toF(Xr[((size_t)dst * 1024 + n) * H + c]);
                float rr = sigm(rp);
                RMb[(size_t)r * HP + c] = __float2bfloat16(rr * Sb[(size_t)r * H + c]);
            }
        }
}

// hs[23+tl] += hs[21-tl] for tl in [0,22)
__global__ __launch_bounds__(256)
void hv_fixup(bf16* __restrict__ hs) {
    int idx = blockIdx.x * 256 + threadIdx.x;
    if (idx >= 22 * SLOT) return;
    int tl = idx / SLOT;
    int rem = idx - tl * SLOT;
    size_t a = (size_t)(23 + tl) * SLOT + rem;
    size_t b = (size_t)(21 - tl) * SLOT + rem;
    hs[a] = __float2bfloat16(toF(hs[a]) + toF(hs[b]));
}

// q_hidden root rows: relu(Qtv) -> qh rows 0..1023 (stride HP)
__global__ __launch_bounds__(256)
void q_root(const float* __restrict__ Qtv, bf16* __restrict__ qh) {
    int idx = blockIdx.x * 256 + threadIdx.x;
    if (idx >= 1024 * H) return;
    int n = idx / H, c = idx - n * H;
    qh[(size_t)n * HP + c] = __float2bfloat16(fmaxf(Qtv[idx], 0.f));
}

// ---------------------------------------------------------------------------
// q_reduce: wave-per-row online softmax + argmax; per-block partials -> qred
// grid = 6144 blocks x 256 threads (4 rows/block)
// ---------------------------------------------------------------------------
__global__ __launch_bounds__(256)
void q_reduce(const float* __restrict__ ql, const int* __restrict__ wid,
              float* __restrict__ qred) {
    int wave = threadIdx.x >> 6, lane = threadIdx.x & 63;
    int r = blockIdx.x * 4 + wave;                 // 0..24575
    int t = r >> 10, n = r & 1023;
    int tgt = wid[n * LW + t];
    const float4* row4 = (const float4*)(ql + (size_t)r * V);   // 195 float4
    float m = -3.4e38f, s = 0.f; int mi = 0x7fffffff;
#pragma unroll
    for (int k = 0; k < 4; k++) {
        int c4 = lane + 64 * k;
        if (c4 < 195) {
            float4 v4 = row4[c4];
            float vv[4] = {v4.x, v4.y, v4.z, v4.w};
#pragma unroll
            for (int e = 0; e < 4; e++) {
                float v = vv[e];
                if (v > m) { s = s * __expf(m - v) + 1.f; m = v; mi = c4 * 4 + e; }
                else s += __expf(v - m);
            }
        }
    }
#pragma unroll
    for (int off = 1; off < 64; off <<= 1) {
        float m2 = __shfl_xor(m, off);
        float s2 = __shfl_xor(s, off);
        int   i2 = __shfl_xor(mi, off);
        if (m2 > m || (m2 == m && i2 < mi)) {
            s = s2 + s * __expf(m - m2);
            m = m2; mi = i2;
        } else {
            s = s + s2 * __expf(m2 - m);
        }
    }
    __shared__ float lred[4][2];
    if (lane == 0) {
        float lse = m + logf(s);
        lred[wave][0] = lse - ql[(size_t)r * V + tgt];
        lred[wave][1] = (mi == tgt) ? 1.f : 0.f;
    }
    __syncthreads();
    if (threadIdx.x == 0) {
        qred[blockIdx.x * 2]     = lred[0][0] + lred[1][0] + lred[2][0] + lred[3][0];
        qred[blockIdx.x * 2 + 1] = lred[0][1] + lred[1][1] + lred[2][1] + lred[3][1];
    }
}

// final q reduction: one block
__global__ __launch_bounds__(256)
void q_final(const float* __restrict__ qred, float* __restrict__ out) {
    int tid = threadIdx.x;
    float L = 0.f, A = 0.f;
    for (int i = tid; i < QBLK; i += 256) { L += qred[2 * i]; A += qred[2 * i + 1]; }
    __shared__ float s1[256], s2[256];
    s1[tid] = L; s2[tid] = A;
    __syncthreads();
    for (int k = 128; k > 0; k >>= 1) {
        if (tid < k) { s1[tid] += s1[tid + k]; s2[tid] += s2[tid + k]; }
        __syncthreads();
    }
    if (tid == 0) {
        out[0] = s1[0] * (1.f / 1024.f);
        out[2] = s2[0] * (1.f / 24576.f);
    }
}

__global__ __launch_bounds__(256)
void p_init(float* __restrict__ pl, const float* __restrict__ Us_b) {
    int idx = blockIdx.x * 256 + threadIdx.x;
    if (idx < PROWS) pl[idx] = Us_b[0];
}

__global__ __launch_bounds__(256)
void p_root(const bf16* __restrict__ XUa, const float* __restrict__ Ptv,
            const float* __restrict__ Us, float* __restrict__ pl) {
    int n = blockIdx.x;
    int tid = threadIdx.x;
    const bf16* xa = XUa + (size_t)n * H;
    const float* pt = Ptv + (size_t)n * H;
    float s = 0.f;
    for (int c = tid; c < H; c += 256)
        s += fmaxf(toF(xa[c]) + pt[c], 0.f) * Us[c];
    __shared__ float red[256];
    red[tid] = s;
    __syncthreads();
    for (int k = 128; k > 0; k >>= 1) {
        if (tid < k) red[tid] += red[tid + k];
        __syncthreads();
    }
    if (tid == 0) atomicAdd(&pl[n], red[0]);
}

// p scan rows (MFMA): hs @ Ub; epilogue relu(+XUa[dst]+Ptv) dot Us -> pl
__global__ __launch_bounds__(256)
void p_gemm(const bf16* __restrict__ hs, const bf16* __restrict__ UbT,
            const bf16* __restrict__ XUa, const float* __restrict__ Ptv,
            const float* __restrict__ Us, float* __restrict__ pl) {
    int tid = threadIdx.x;
    int lane = tid & 63, wave = tid >> 6;
    int wx = wave & 1, wy = wave >> 1;
    int lrow = lane & 15, quad = lane >> 4;
    int row0 = blockIdx.y * 64, col0 = blockIdx.x * 64;
    const bf16* a0 = hs + (size_t)(row0 + wy * 32 + lrow) * HP + quad * 8;
    const bf16* b0 = UbT + (size_t)(col0 + wx * 32 + lrow) * KP + quad * 8;
    f32x4 acc[2][2] = {};
    for (int k = 0; k < 15; k++) {
        short8 af0 = ld8(a0 + k * 32);
        short8 af1 = ld8(a0 + (size_t)16 * HP + k * 32);
        short8 bf0 = ld8(b0 + k * 32);
        short8 bf1 = ld8(b0 + 16 * KP + k * 32);
        acc[0][0] = MFMA16(af0, bf0, acc[0][0]);
        acc[0][1] = MFMA16(af0, bf1, acc[0][1]);
        acc[1][0] = MFMA16(af1, bf0, acc[1][0]);
        acc[1][1] = MFMA16(af1, bf1, acc[1][1]);
    }
    __shared__ float red[64][32];
#pragma unroll
    for (int i = 0; i < 2; i++)
#pragma unroll
        for (int e = 0; e < 4; e++) {
            int rl = wy * 32 + i * 16 + quad * 4 + e;
            int r = row0 + rl;
            int t = r >> 10, n = r & 1023;
            int dst = (t < 23) ? (t + 1) : (45 - t);
            float partial = 0.f;
#pragma unroll
            for (int j = 0; j < 2; j++) {
                int c = col0 + wx * 32 + j * 16 + lrow;
                if (c < H) {
                    float h = fmaxf(acc[i][j][e] + toF(XUa[((size_t)dst * 1024 + n) * H + c])
                                    + Ptv[(size_t)n * H + c], 0.f);
                    partial += h * Us[c];
                }
            }
            red[rl][wx * 16 + lrow] = partial;
        }
    __syncthreads();
    if (tid < 64) {
        float s = 0.f;
#pragma unroll
        for (int k = 0; k < 32; k++) s += red[tid][k];
        atomicAdd(&pl[1024 + row0 + tid], s);
    }
}

// BCE loss + accuracy over 48128 rows; target = (r < 23552)
__global__ __launch_bounds__(256)
void p_final(const float* __restrict__ pl, float* __restrict__ out) {
    int r = blockIdx.x * 256 + threadIdx.x;
    int tid = threadIdx.x;
    float loss = 0.f, acc = 0.f;
    if (r < PROWS) {
        float l = pl[r];
        int tgt = (r < PTGT) ? 1 : 0;
        float x = tgt ? -l : l;
        loss = fmaxf(x, 0.f) + log1pf(expf(-fabsf(x)));
        int pred = (l > 0.f) ? 1 : 0;
        acc = (pred == tgt) ? 1.f : 0.f;
    }
    __shared__ float s1[256], s2[256];
    s1[tid] = loss; s2[tid] = acc;
    __syncthreads();
    for (int k = 128; k > 0; k >>= 1) {
        if (tid < k) { s1[tid] += s1[tid + k]; s2[tid] += s2[tid + k]; }
        __syncthreads();
    }
    if (tid == 0) {
        atomicAdd(&out[1], s1[0] * (1.f / 1024.f));
        atomicAdd(&out[3], s2[0] * (1.f / 48128.f));
    }
}

// ---------------------------------------------------------------------------
extern "C" void kernel_launch(void* const* d_in, const int* in_sizes, int n_in,
                              void* d_out, int out_size, void* d_ws, size_t ws_size,
                              hipStream_t stream) {
    const int*   wid  = (const int*)  d_in[0];
    const float* tv   = (const float*)d_in[1];
    const float* emb  = (const float*)d_in[2];
    const float* W_w  = (const float*)d_in[3];
    const float* W_b  = (const float*)d_in[4];
    const float* U_w  = (const float*)d_in[5];
    const float* U_b  = (const float*)d_in[6];
    const float* Wo_w = (const float*)d_in[7];
    const float* Wo_b = (const float*)d_in[8];
    const float* Us_w = (const float*)d_in[9];
    const float* Us_b = (const float*)d_in[10];
    const float* Wz_w = (const float*)d_in[11];
    const float* Wz_b = (const float*)d_in[12];
    const float* Wr_w = (const float*)d_in[13];
    const float* Ur_w = (const float*)d_in[14];
    const float* Ur_b = (const float*)d_in[15];
    const float* Wh_w = (const float*)d_in[16];
    const float* Wh_b = (const float*)d_in[17];
    float* out = (float*)d_out;

    // ---- workspace layout (bytes), total ~147 MiB ----
    char* base = (char*)d_ws;
    const size_t XBb = (size_t)QROWS * H * 2;
    bf16*  Xz   = (bf16*)(base);
    bf16*  Xh   = (bf16*)(base + XBb);
    bf16*  Xr   = (bf16*)(base + 2 * XBb);
    bf16*  XUa  = (bf16*)(base + 3 * XBb);
    bf16*  hs   = (bf16*)(base + 4 * XBb);               // 46 slots x 1024 x HP
    bf16*  x_all = hs;                                   // alias (dead before scan)
    char*  p1   = base + 4 * XBb + (size_t)NE * SLOT * 2;
    bf16*  RMb  = (bf16*)p1;                p1 += (size_t)SROWS * HP * 2;
    float* Sb   = (float*)p1;               p1 += (size_t)SROWS * H * 4;
    float* Qtv  = (float*)p1;               p1 += (size_t)1024 * H * 4;
    float* Ptv  = (float*)p1;               p1 += (size_t)1024 * H * 4;
    float* pl   = (float*)p1;               p1 += (size_t)PROWS * 4;
    float* qred = (float*)p1;               p1 += (size_t)QBLK * 2 * 4;
    bf16*  BT   = (bf16*)p1;
    const size_t BTS = (size_t)512 * KP;
    bf16 *WztT = BT,           *WhtT = BT + BTS,     *WrT = BT + 2*BTS,
         *UaT  = BT + 3*BTS,   *WzbT = BT + 4*BTS,   *WhbT = BT + 5*BTS,
         *UrT  = BT + 6*BTS,   *UbT  = BT + 7*BTS,   *WtopT = BT + 8*BTS,
         *WoT  = BT + 9*BTS;                             // 832*KP
    // q-path aliases (used after p path completes):
    bf16*  qh = (bf16*)base;                             // 24576 x HP bf16
    float* ql = (float*)(base + (size_t)QROWS * HP * 2); // 24576 x 780 f32

    // ---- init + weight prep ----
    zero_init<<<(SROWS * H + 255) / 256, 256, 0, stream>>>(out, Sb, SROWS * H);
    int btg = (512 * KP + 255) / 256;
    make_bt<<<btg, 256, 0, stream>>>(Wz_w,            H, H, H, WztT, 512);
    make_bt<<<btg, 256, 0, stream>>>(Wh_w,            H, H, H, WhtT, 512);
    make_bt<<<btg, 256, 0, stream>>>(Wr_w,            H, H, H, WrT,  512);
    make_bt<<<btg, 256, 0, stream>>>(U_w,             H, H, H, UaT,  512);
    make_bt<<<btg, 256, 0, stream>>>(Wz_w + 450*450,  H, H, H, WzbT, 512);
    make_bt<<<btg, 256, 0, stream>>>(Wh_w + 450*450,  H, H, H, WhbT, 512);
    make_bt<<<btg, 256, 0, stream>>>(Ur_w,            H, H, H, UrT,  512);
    make_bt<<<btg, 256, 0, stream>>>(U_w + 450*450,   H, H, H, UbT,  512);
    make_bt<<<btg, 256, 0, stream>>>(W_w,             H, H, H, WtopT, 512);
    make_bt<<<(832 * KP + 255) / 256, 256, 0, stream>>>(Wo_w, H, V, V, WoT, 832);

    // ---- embedding gather + per-node precomputes ----
    gather_x<<<(24 * 1024 * 225 + 255) / 256, 256, 0, stream>>>(emb, wid, x_all);
    dim3 gPre(8, QROWS / 64);
    gemm_mfma<bf16><<<gPre, 256, 0, stream>>>(x_all, HP, WztT, H, Xz,  H, Wz_b, (const float*)nullptr, H, 0);
    gemm_mfma<bf16><<<gPre, 256, 0, stream>>>(x_all, HP, WhtT, H, Xh,  H, Wh_b, (const float*)nullptr, H, 0);
    gemm_mfma<bf16><<<gPre, 256, 0, stream>>>(x_all, HP, WrT,  H, Xr,  H, Ur_b, (const float*)nullptr, H, 0);
    gemm_mfma<bf16><<<gPre, 256, 0, stream>>>(x_all, HP, UaT,  H, XUa, H, (const float*)nullptr, (const float*)nullptr, H, 0);

    tv_gemm<<<dim3(2, 1024), 256, 0, stream>>>(tv, W_w + 450*450, W_b, Qtv);
    tv_gemm<<<dim3(2, 1024), 256, 0, stream>>>(tv, U_w + 900*450, U_b, Ptv);

    // ---- sequential scan: 23 steps, fwd+bwd chains batched (M=2048) ----
    dim3 gScan(8, SROWS / 64);
    for (int u = 0; u < 23; u++) {
        const bf16* AsF = hs + (size_t)(u - 1) * SLOT;        // valid only u>0
        const bf16* AsB = hs + (size_t)(22 + u) * SLOT;
        scan_k1<<<gScan, 256, 0, stream>>>(AsF, AsB, RMb, WzbT, WhbT, Xz, Xh,
                                           Sb, hs + (size_t)u * SLOT,
                                           hs + (size_t)(23 + u) * SLOT, u, u == 0 ? 1 : 0);
        if (u < 22)
            scan_k2<<<gScan, 256, 0, stream>>>(hs + (size_t)u * SLOT, hs + (size_t)(23 + u) * SLOT,
                                               UrT, Xr, Sb, RMb, u);
    }
    hv_fixup<<<(22 * SLOT + 255) / 256, 256, 0, stream>>>(hs);

    // ---- p path (before q aliases X blocks / hs) ----
    p_init<<<(PROWS + 255) / 256, 256, 0, stream>>>(pl, Us_b);
    p_root<<<1024, 256, 0, stream>>>(XUa, Ptv, Us_w, pl);
    dim3 gP(8, (NE * 1024) / 64);
    p_gemm<<<gP, 256, 0, stream>>>(hs, UbT, XUa, Ptv, Us_w, pl);
    p_final<<<PROWS / 256, 256, 0, stream>>>(pl, out);

    // ---- q path (qh over Xz/Xh; ql over Xr/XUa/hs-head) ----
    q_root<<<(1024 * H + 255) / 256, 256, 0, stream>>>(Qtv, qh);
    dim3 gQh(8, (NF * 1024) / 64);
    gemm_mfma<bf16><<<gQh, 256, 0, stream>>>(hs, HP, WtopT, H, qh + (size_t)1024 * HP, HP,
                                             (const float*)nullptr, Qtv, H, 1);
    dim3 gQl(13, QROWS / 64);
    gemm_mfma<float><<<gQl, 256, 0, stream>>>(qh, HP, WoT, V, ql, V, Wo_b, (const float*)nullptr, H, 0);
    q_reduce<<<QBLK, 256, 0, stream>>>(ql, wid, qred);
    q_final<<<1, 256, 0, stream>>>(qred, out);

    (void)in_sizes; (void)n_in; (void)out_size; (void)ws_size;
}